// Round 6
// baseline (336.102 us; speedup 1.0000x reference)
//
#include <hip/hip_runtime.h>
#include <hip/hip_bf16.h>

#define T_LEN 48000
#define NCH   64
#define NB    4
#define CT    256    // scan chunk length (96000/256 = 375 chunks)
#define WU    256    // scan warm-up steps (0.96^256~2.9e-5; thr err -> spike flips only)

static constexpr double DTd    = 1.0 / 48000.0;
static constexpr double ALPHAd = DTd / (DTd + 0.0005);   // exactly 0.04
static constexpr float  AF     = (float)ALPHAd;
static constexpr float  OMF    = (float)(1.0 - ALPHAd);  // 0.96

typedef __attribute__((ext_vector_type(8))) short bf16x8;
typedef __attribute__((ext_vector_type(4))) float f32x4;
typedef bf16x8 bf16x8_u __attribute__((aligned(4)));     // 4B-aligned 16B load

static __device__ __forceinline__ unsigned short f2bf(float f) {
    __hip_bfloat16 h = __float2bfloat16(f);
    unsigned short u; __builtin_memcpy(&u, &h, 2);
    return u;
}

// ---------------------------------------------------------------- K0: fused prep
// role (blockIdx.y) 0..3: Afrag swizzle for group g (+kstart[g*16]); role 4: x -> bf16 copies
__global__ __launch_bounds__(256) void prep_all(
        const float* __restrict__ x, const float* __restrict__ Km,
        int* __restrict__ kstart, unsigned short* __restrict__ xc,
        unsigned short* __restrict__ Afrag,
        int L, int SMAX4, int SMAXA, int PAD, int XCAP) {
    const int role = blockIdx.y;
    if (role < 4) {
        const int g = role, s = blockIdx.x;
        if (s >= SMAX4) return;
        __shared__ int smin;
        if (threadIdx.x == 0) smin = L - 1;
        __syncthreads();
        const float* row = Km + (size_t)(g * 16) * L;
        int local = L - 1;
        for (int i = threadIdx.x; i < L; i += 256)
            if (row[i] != 0.0f) { local = i; break; }
        atomicMin(&smin, local);
        __syncthreads();
        const int ks = smin;
        if (s == 0 && threadIdx.x == 0) kstart[g * 16] = ks;
        if (threadIdx.x < 64) {
            const int lane = threadIdx.x;
            const int Lg = L - ks;
            const int r = lane & 15, khi = lane >> 4;
            const float* kr = Km + (size_t)(g * 16 + r) * L + ks;
            const size_t off = ((size_t)(g * SMAXA + s) * 64 + lane) * 8;
            #pragma unroll
            for (int jj = 0; jj < 8; ++jj) {
                const int q = 32 * s + 8 * khi + jj;
                Afrag[off + jj] = (q < Lg) ? f2bf(kr[q]) : (unsigned short)0;
            }
        }
    } else {
        const int idx = blockIdx.x * 256 + threadIdx.x;
        if (idx >= NB * XCAP) return;
        const int b = idx / XCAP, j = idx % XCAP;
        const float* xb = x + (size_t)b * T_LEN;
        const int t0 = j - PAD, t1 = t0 + 1;
        xc[((size_t)b * 2 + 0) * XCAP + j] = (t0 >= 0 && t0 < T_LEN) ? f2bf(xb[t0]) : (unsigned short)0;
        xc[((size_t)b * 2 + 1) * XCAP + j] = (t1 >= 0 && t1 < T_LEN) ? f2bf(xb[t1]) : (unsigned short)0;
    }
}

// ---------------------------------------------------------------- conv block body
// Toeplitz register reuse (B(j+2,s)==B(j,s+1)); A staged via double-buffered LDS.
__device__ __forceinline__ void conv_block(
        const unsigned short* __restrict__ xc, const unsigned short* __restrict__ Afrag,
        const int* __restrict__ kstart, unsigned short* __restrict__ rect,
        int L, int SMAXA, int PAD, int XCAP, int g, int t0) {
    __shared__ short As[2][2048];                      // [buf][4 K-steps x 64 lanes x 8]
    const int lane = threadIdx.x & 63;
    const int w    = threadIdx.x >> 6;                 // wave = batch
    const int ks   = kstart[g * 16];
    const int Lg   = L - ks;
    const int nst4 = (((Lg + 31) >> 5) + 3) & ~3;      // K-steps, padded to x4 (A zero-padded)
    const int nl   = lane & 15, khi = lane >> 4;
    const int i0   = t0 + nl + 8 * khi - (Lg - 1);     // x index for (s=0, tile 0)
    const int p    = i0 & 1;                           // parity fixed across s and tiles
    const unsigned short* xp = xc + ((size_t)(w * 2 + p)) * XCAP + (PAD + i0 - p);
    const unsigned short* ap = Afrag + ((size_t)(g * SMAXA + w) * 64 + (size_t)lane) * 8;

    f32x4 acc[8];
    #pragma unroll
    for (int j = 0; j < 8; ++j) acc[j] = (f32x4){0.f, 0.f, 0.f, 0.f};
    bf16x8 bx[8];
    #pragma unroll
    for (int j = 0; j < 8; ++j) bx[j] = *(const bf16x8_u*)(xp + 16 * j);

    {   // initial stage: s-block 0 (wave w stages K-step row w)
        const bf16x8 st = *(const bf16x8*)(ap);
        *(bf16x8*)(&As[0][w * 512 + lane * 8]) = st;
    }
    __syncthreads();

    int q = 0;
    for (int s = 0; s < nst4; s += 4) {
        const bf16x8 nxt = *(const bf16x8*)(ap + (size_t)(s + 4) * 512);
        const bf16x8 a0 = *(const bf16x8*)(&As[q][          lane * 8]);
        const bf16x8 a1 = *(const bf16x8*)(&As[q][ 512 + lane * 8]);
        const bf16x8 a2 = *(const bf16x8*)(&As[q][1024 + lane * 8]);
        const bf16x8 a3 = *(const bf16x8*)(&As[q][1536 + lane * 8]);
        #pragma unroll
        for (int j = 0; j < 8; ++j)
            acc[j] = __builtin_amdgcn_mfma_f32_16x16x32_bf16(a0, bx[j & 7], acc[j], 0, 0, 0);
        bx[0] = *(const bf16x8_u*)(xp + 128);
        bx[1] = *(const bf16x8_u*)(xp + 144);
        #pragma unroll
        for (int j = 0; j < 8; ++j)
            acc[j] = __builtin_amdgcn_mfma_f32_16x16x32_bf16(a1, bx[(2 + j) & 7], acc[j], 0, 0, 0);
        bx[2] = *(const bf16x8_u*)(xp + 160);
        bx[3] = *(const bf16x8_u*)(xp + 176);
        #pragma unroll
        for (int j = 0; j < 8; ++j)
            acc[j] = __builtin_amdgcn_mfma_f32_16x16x32_bf16(a2, bx[(4 + j) & 7], acc[j], 0, 0, 0);
        bx[4] = *(const bf16x8_u*)(xp + 192);
        bx[5] = *(const bf16x8_u*)(xp + 208);
        #pragma unroll
        for (int j = 0; j < 8; ++j)
            acc[j] = __builtin_amdgcn_mfma_f32_16x16x32_bf16(a3, bx[(6 + j) & 7], acc[j], 0, 0, 0);
        bx[6] = *(const bf16x8_u*)(xp + 224);
        bx[7] = *(const bf16x8_u*)(xp + 240);
        *(bf16x8*)(&As[q ^ 1][w * 512 + lane * 8]) = nxt;
        __syncthreads();
        q ^= 1;
        xp += 128;
    }

    // D layout: col(time)=lane&15, row(channel)=4*(lane>>4)+v   [m89-verified]
    unsigned short* rp = rect + (size_t)(w * NCH + g * 16 + 4 * khi) * T_LEN + t0 + nl;
    #pragma unroll
    for (int j = 0; j < 8; ++j) {
        #pragma unroll
        for (int v = 0; v < 4; ++v)
            rp[(size_t)v * T_LEN + 16 * j] = f2bf(fmaxf(acc[j][v], 0.f));
    }
}

// ---------------------------------------------------------------- scan wave body
static __device__ __forceinline__ float bfw(unsigned int w, int odd) {
    return __uint_as_float(odd ? (w & 0xFFFF0000u) : (w << 16));
}
static __device__ __forceinline__ unsigned int getw(const uint4& u, int i) {
    return i == 0 ? u.x : i == 1 ? u.y : i == 2 ? u.z : u.w;  // i is compile-time
}

__device__ __forceinline__ void scan_step(float r0, float r1, float r2, float r3,
        int u, bool store, int c, float* __restrict__ out0, float* __restrict__ out1,
        float& s0, float& s1, float& s2, float& s3, float& thr) {
    s0 = AF * r0 + OMF * s0;
    s1 = AF * r1 + OMF * s1;
    s2 = AF * r2 + OMF * s2;
    s3 = AF * r3 + OMF * s3;
    const float k0 = (s0 > thr) ? 1.0f : 0.0f;
    const float k1 = (s1 > thr) ? 1.0f : 0.0f;
    const float k2 = (s2 > thr) ? 1.0f : 0.0f;
    const float k3 = (s3 > thr) ? 1.0f : 0.0f;
    const float cnt = (k0 + k1) + (k2 + k3);
    thr = thr + 0.01f * (cnt * 0.25f) + 0.01f * (0.1f - thr);
    if (store) {
        const int e  = (u >= T_LEN) ? 1 : 0;
        const int tt = u - (e ? T_LEN : 0);
        const int o1 = ((e * T_LEN + tt) << 6) + c;          // [B][2][T][C]
        out1[o1]                   = s0;
        out1[o1 + 2 * T_LEN * NCH] = s1;
        out1[o1 + 4 * T_LEN * NCH] = s2;
        out1[o1 + 6 * T_LEN * NCH] = s3;
        const int o0 = (tt << 7) + (e << 6) + c;             // [B][T][2C]
        out0[o0]                   = k0;
        out0[o0 + T_LEN * 128]     = k1;
        out0[o0 + 2 * T_LEN * 128] = k2;
        out0[o0 + 3 * T_LEN * 128] = k3;
    }
}

#define LOAD_SG(buf, ug) do {                                                          \
    const int tt_ = ((ug) < T_LEN) ? (ug) : ((ug) - T_LEN);                            \
    _Pragma("unroll")                                                                  \
    for (int b_ = 0; b_ < 4; ++b_) {                                                   \
        const uint4* p_ = (const uint4*)(rect + (size_t)(b_ * NCH + c) * T_LEN + tt_); \
        buf[b_][0] = p_[0];                                                            \
        buf[b_][1] = p_[1];                                                            \
    }                                                                                  \
} while (0)

#define PROC_SG(buf, ug) do {                                                          \
    _Pragma("unroll")                                                                  \
    for (int q_ = 0; q_ < 16; ++q_) {                                                  \
        const float r0_ = bfw(getw(buf[0][q_ >> 3], (q_ >> 1) & 3), q_ & 1);           \
        const float r1_ = bfw(getw(buf[1][q_ >> 3], (q_ >> 1) & 3), q_ & 1);           \
        const float r2_ = bfw(getw(buf[2][q_ >> 3], (q_ >> 1) & 3), q_ & 1);           \
        const float r3_ = bfw(getw(buf[3][q_ >> 3], (q_ >> 1) & 3), q_ & 1);           \
        scan_step(r0_, r1_, r2_, r3_, (ug) + q_, STORE, c, out0, out1, s0, s1, s2, s3, thr); \
    }                                                                                  \
} while (0)

template <bool STORE>
__device__ __forceinline__ void scan_range(int from, int to, int c,
        const unsigned short* __restrict__ rect, float* __restrict__ out0, float* __restrict__ out1,
        float& s0, float& s1, float& s2, float& s3, float& thr) {
    if (from >= to) return;                // (to-from) is a multiple of 32
    uint4 bufA[4][2], bufB[4][2];
    LOAD_SG(bufA, from);
    for (int ug = from; ug < to; ug += 32) {
        LOAD_SG(bufB, ug + 16);
        PROC_SG(bufA, ug);
        if (ug + 32 < to) LOAD_SG(bufA, ug + 32);
        PROC_SG(bufB, ug + 16);
    }
}

__device__ __forceinline__ void scan_wave(const unsigned short* __restrict__ rect,
                                          float* __restrict__ out, int k, int c) {
    const int u0   = k * CT;
    const int uend = u0 + CT;                           // 96000 % CT == 0
    const int w0   = (u0 >= WU) ? (u0 - WU) : 0;
    float s0 = 0.f, s1 = 0.f, s2 = 0.f, s3 = 0.f, thr = 0.1f;
    float* out0 = out;
    float* out1 = out + (size_t)NB * T_LEN * 2 * NCH;   // 24,576,000
    scan_range<false>(w0, u0,   c, rect, out0, out1, s0, s1, s2, s3, thr);
    scan_range<true >(u0, uend, c, rect, out0, out1, s0, s1, s2, s3, thr);
}

// ---------------------------------------------------------------- mixed pipeline node
// blocks [0, ncv*4): conv stage blocks (g = bx/ncv longest-first, tile = ct0 + bx%ncv)
// blocks [ncv*4, ...): scan waves, chunk ids (lo1 + i) for i<n1, then (lo2 + i-n1)
__global__ __launch_bounds__(256) void mixed_kernel(
        const unsigned short* __restrict__ xc, const unsigned short* __restrict__ Afrag,
        const int* __restrict__ kstart, unsigned short* __restrict__ rect,
        float* __restrict__ out,
        int L, int SMAXA, int PAD, int XCAP,
        int ncv, int ct0, int lo1, int n1, int lo2, int n2) {
    const int bx = (int)blockIdx.x;
    if (bx < ncv * 4) {
        conv_block(xc, Afrag, kstart, rect, L, SMAXA, PAD, XCAP,
                   bx / ncv, (ct0 + bx % ncv) * 128);
    } else {
        const int sidx = (bx - ncv * 4) * 4 + (int)(threadIdx.x >> 6);
        if (sidx >= n1 + n2) return;
        const int k = (sidx < n1) ? (lo1 + sidx) : (lo2 + (sidx - n1));
        scan_wave(rect, out, k, (int)(threadIdx.x & 63));
    }
}

// ---------------------------------------------------------------- launch
extern "C" void kernel_launch(void* const* d_in, const int* in_sizes, int n_in,
                              void* d_out, int out_size, void* d_ws, size_t ws_size,
                              hipStream_t stream) {
    const float* x  = (const float*)d_in[0];       // [4, 48000] fp32
    const float* Km = (const float*)d_in[1];       // [64, L]    fp32
    const int L     = in_sizes[1] / NCH;
    const int SMAX  = (L + 31) / 32;
    const int SMAX4 = (SMAX + 3) & ~3;
    const int SMAXA = SMAX4 + 4;                   // +4-row guard for A prefetch
    const int PAD   = (L + 1) & ~1;                // even, >= L-1
    const int XCAP  = PAD + T_LEN + 512;           // even; covers padded-K over-read

    char* w = (char*)d_ws;
    int* kstart = (int*)w;
    unsigned short* xc = (unsigned short*)(w + 512);
    const size_t xc_bytes = (size_t)NB * 2 * XCAP * 2;
    unsigned short* Afrag = (unsigned short*)(w + 512 + ((xc_bytes + 15) & ~(size_t)15));
    const size_t a_bytes = (size_t)4 * SMAXA * 64 * 8 * 2;
    unsigned short* rect = (unsigned short*)((char*)Afrag + ((a_bytes + 15) & ~(size_t)15));

    const int pxBlocks = (NB * XCAP + 255) / 256;
    dim3 pgrid(pxBlocks > SMAX4 ? pxBlocks : SMAX4, 5);
    prep_all<<<pgrid, 256, 0, stream>>>(x, Km, kstart, xc, Afrag, L, SMAX4, SMAXA, PAD, XCAP);

    // 4 conv stages (375 t-tiles = 94+94+94+93). Scan chunk k requires rect time:
    //   k<=186: (k+1)*256-1 ; k in {187,188}: 47999 ; k>=189: (k+1)*256-1-48000
    // Stage i completes rect t < D_i = {12032, 24064, 36096, 48000}. Chunks are
    // scheduled in the first node whose preceding stages cover their requirement.
    struct NodeCfg { int ncv, ct0, lo1, n1, lo2, n2; };
    const NodeCfg nodes[5] = {
        { 94,   0,   0,  0,   0,  0 },   // conv [0,94)
        { 94,  94,   0, 47, 189, 45 },   // conv [94,188)  + scan k in [0,46]   u [189,233]
        { 94, 188,  47, 47, 234, 47 },   // conv [188,282) + scan k in [47,93]  u [234,280]
        { 93, 282,  94, 47, 281, 47 },   // conv [282,375) + scan k in [94,140] u [281,327]
        {  0,   0, 141, 48, 328, 47 },   //                  scan k in [141,188] u [328,374]
    };
    for (int i = 0; i < 5; ++i) {
        const NodeCfg& nd = nodes[i];
        const int nscan_blocks = (nd.n1 + nd.n2 + 3) / 4;
        const int grid = nd.ncv * 4 + nscan_blocks;
        mixed_kernel<<<grid, 256, 0, stream>>>(xc, Afrag, kstart, rect, (float*)d_out,
                                               L, SMAXA, PAD, XCAP,
                                               nd.ncv, nd.ct0, nd.lo1, nd.n1, nd.lo2, nd.n2);
    }
}

// Round 8
// 110.718 us; speedup vs baseline: 3.0357x; 3.0357x over previous
//
#include <hip/hip_runtime.h>
#include <hip/hip_bf16.h>

#define T_LEN 48000
#define NCH   64
#define NB    4
#define CT    128    // scan chunk length (96000/128 = 750 chunks)
#define WU    256    // scan warm-up steps (0.96^256~2.9e-5; thr err -> spike flips only)

static constexpr double DTd    = 1.0 / 48000.0;
static constexpr double ALPHAd = DTd / (DTd + 0.0005);   // exactly 0.04
static constexpr float  AF     = (float)ALPHAd;
static constexpr float  OMF    = (float)(1.0 - ALPHAd);  // 0.96

typedef __attribute__((ext_vector_type(8))) short bf16x8;
typedef __attribute__((ext_vector_type(4))) float f32x4;
typedef bf16x8 bf16x8_u __attribute__((aligned(4)));     // 4B-aligned 16B load

static __device__ __forceinline__ unsigned short f2bf(float f) {
    __hip_bfloat16 h = __float2bfloat16(f);
    unsigned short u; __builtin_memcpy(&u, &h, 2);
    return u;
}

// ---------------------------------------------------------------- K0: fused prep
// role (blockIdx.y) 0..3: Afrag swizzle for group g (+kstart[g*16]); role 4: x -> bf16 copies
__global__ __launch_bounds__(256) void prep_all(
        const float* __restrict__ x, const float* __restrict__ Km,
        int* __restrict__ kstart, unsigned short* __restrict__ xc,
        unsigned short* __restrict__ Afrag,
        int L, int SMAX4, int SMAXA, int PAD, int XCAP) {
    const int role = blockIdx.y;
    if (role < 4) {
        const int g = role, s = blockIdx.x;
        if (s >= SMAX4) return;
        __shared__ int smin;
        if (threadIdx.x == 0) smin = L - 1;
        __syncthreads();
        const float* row = Km + (size_t)(g * 16) * L;
        int local = L - 1;
        for (int i = threadIdx.x; i < L; i += 256)
            if (row[i] != 0.0f) { local = i; break; }
        atomicMin(&smin, local);
        __syncthreads();
        const int ks = smin;
        if (s == 0 && threadIdx.x == 0) kstart[g * 16] = ks;
        if (threadIdx.x < 64) {
            const int lane = threadIdx.x;
            const int Lg = L - ks;
            const int r = lane & 15, khi = lane >> 4;
            const float* kr = Km + (size_t)(g * 16 + r) * L + ks;
            const size_t off = ((size_t)(g * SMAXA + s) * 64 + lane) * 8;
            #pragma unroll
            for (int jj = 0; jj < 8; ++jj) {
                const int q = 32 * s + 8 * khi + jj;
                Afrag[off + jj] = (q < Lg) ? f2bf(kr[q]) : (unsigned short)0;
            }
        }
    } else {
        const int idx = blockIdx.x * 256 + threadIdx.x;
        if (idx >= NB * XCAP) return;
        const int b = idx / XCAP, j = idx % XCAP;
        const float* xb = x + (size_t)b * T_LEN;
        const int t0 = j - PAD, t1 = t0 + 1;
        xc[((size_t)b * 2 + 0) * XCAP + j] = (t0 >= 0 && t0 < T_LEN) ? f2bf(xb[t0]) : (unsigned short)0;
        xc[((size_t)b * 2 + 1) * XCAP + j] = (t1 >= 0 && t1 < T_LEN) ? f2bf(xb[t1]) : (unsigned short)0;
    }
}

// ---------------------------------------------------------------- K1: MFMA filterbank -> rect bf16 [B][C][T]
// Toeplitz register reuse (B(j+2,s)==B(j,s+1)); A staged via double-buffered LDS.
__global__ __launch_bounds__(256) void conv_mfma(
        const unsigned short* __restrict__ xc, const unsigned short* __restrict__ Afrag,
        const int* __restrict__ kstart, unsigned short* __restrict__ rect,
        int L, int SMAXA, int PAD, int XCAP) {
    const int lane = threadIdx.x & 63;
    const int w    = threadIdx.x >> 6;                 // wave = batch
    const int g    = blockIdx.y;
    const int t0   = blockIdx.x * 128;
    const int ks   = kstart[g * 16];
    const int Lg   = L - ks;
    const int nst4 = (((Lg + 31) >> 5) + 3) & ~3;      // K-steps, padded to x4 (A zero-padded)
    const int nl   = lane & 15, khi = lane >> 4;
    const int i0   = t0 + nl + 8 * khi - (Lg - 1);     // x index for (s=0, tile 0)
    const int p    = i0 & 1;                           // parity fixed across s and tiles
    const unsigned short* xp = xc + ((size_t)(w * 2 + p)) * XCAP + (PAD + i0 - p);
    const unsigned short* ap = Afrag + ((size_t)(g * SMAXA + w) * 64 + (size_t)lane) * 8;

    __shared__ short As[2][2048];                      // [buf][4 K-steps x 64 lanes x 8]

    f32x4 acc[8];
    #pragma unroll
    for (int j = 0; j < 8; ++j) acc[j] = (f32x4){0.f, 0.f, 0.f, 0.f};
    bf16x8 bx[8];
    #pragma unroll
    for (int j = 0; j < 8; ++j) bx[j] = *(const bf16x8_u*)(xp + 16 * j);

    {   // initial stage: s-block 0 (wave w stages K-step row w)
        const bf16x8 st = *(const bf16x8*)(ap);
        *(bf16x8*)(&As[0][w * 512 + lane * 8]) = st;
    }
    __syncthreads();

    int q = 0;
    for (int s = 0; s < nst4; s += 4) {
        const bf16x8 nxt = *(const bf16x8*)(ap + (size_t)(s + 4) * 512);
        const bf16x8 a0 = *(const bf16x8*)(&As[q][          lane * 8]);
        const bf16x8 a1 = *(const bf16x8*)(&As[q][ 512 + lane * 8]);
        const bf16x8 a2 = *(const bf16x8*)(&As[q][1024 + lane * 8]);
        const bf16x8 a3 = *(const bf16x8*)(&As[q][1536 + lane * 8]);
        #pragma unroll
        for (int j = 0; j < 8; ++j)
            acc[j] = __builtin_amdgcn_mfma_f32_16x16x32_bf16(a0, bx[j & 7], acc[j], 0, 0, 0);
        bx[0] = *(const bf16x8_u*)(xp + 128);
        bx[1] = *(const bf16x8_u*)(xp + 144);
        #pragma unroll
        for (int j = 0; j < 8; ++j)
            acc[j] = __builtin_amdgcn_mfma_f32_16x16x32_bf16(a1, bx[(2 + j) & 7], acc[j], 0, 0, 0);
        bx[2] = *(const bf16x8_u*)(xp + 160);
        bx[3] = *(const bf16x8_u*)(xp + 176);
        #pragma unroll
        for (int j = 0; j < 8; ++j)
            acc[j] = __builtin_amdgcn_mfma_f32_16x16x32_bf16(a2, bx[(4 + j) & 7], acc[j], 0, 0, 0);
        bx[4] = *(const bf16x8_u*)(xp + 192);
        bx[5] = *(const bf16x8_u*)(xp + 208);
        #pragma unroll
        for (int j = 0; j < 8; ++j)
            acc[j] = __builtin_amdgcn_mfma_f32_16x16x32_bf16(a3, bx[(6 + j) & 7], acc[j], 0, 0, 0);
        bx[6] = *(const bf16x8_u*)(xp + 224);
        bx[7] = *(const bf16x8_u*)(xp + 240);
        *(bf16x8*)(&As[q ^ 1][w * 512 + lane * 8]) = nxt;
        __syncthreads();
        q ^= 1;
        xp += 128;
    }

    // D layout: col(time)=lane&15, row(channel)=4*(lane>>4)+v   [m89-verified]
    unsigned short* rp = rect + (size_t)(w * NCH + g * 16 + 4 * khi) * T_LEN + t0 + nl;
    #pragma unroll
    for (int j = 0; j < 8; ++j) {
        #pragma unroll
        for (int v = 0; v < 4; ++v)
            rp[(size_t)v * T_LEN + 16 * j] = f2bf(fmaxf(acc[j][v], 0.f));
    }
}

// ---------------------------------------------------------------- K2: rect [B][C][T] -> rect_T [T][C*4+B]
// Scan-side reads become 512B-contiguous per wave-step (8 lines vs 512 per 16 steps).
__global__ __launch_bounds__(256) void transpose_rect(
        const unsigned short* __restrict__ rect, unsigned short* __restrict__ rectT) {
    const int tb  = blockIdx.x * 64;
    const int tid = threadIdx.x;
    __shared__ unsigned short S[4 * 64 * 72];          // row stride 72 (16B-mult, bank-spread)

    {   // coalesced read: thread (c = tid>>2, q = tid&3) loads 2 uint4 per batch
        const int c = tid >> 2, qq = tid & 3;
        #pragma unroll
        for (int b = 0; b < 4; ++b) {
            #pragma unroll
            for (int k = 0; k < 2; ++k) {
                const int i16 = qq + 4 * k;            // 16B chunk 0..7 within the 64-t row
                const uint4 v = *(const uint4*)(rect + (size_t)(b * NCH + c) * T_LEN + tb + i16 * 8);
                *(uint4*)(&S[(b * 64 + c) * 72 + i16 * 8]) = v;
            }
        }
    }
    __syncthreads();
    {   // write: thread (r = tid>>2, pp = tid&3) writes 8 uint4 chunks of row (tb+r)
        // FIX(R7): cover all 32 chunks per 256-short row (m = pp + 4*mm, mm<8)
        const int r = tid >> 2, pp = tid & 3;
        #pragma unroll
        for (int mm = 0; mm < 8; ++mm) {
            const int m = pp + 4 * mm;                 // uint4 index in row: cb 8m..8m+7
            unsigned short tmp[8];
            #pragma unroll
            for (int k = 0; k < 8; ++k) {              // cb = c*4 + b
                const int cc = 2 * m + (k >> 2), bb = k & 3;
                tmp[k] = S[(bb * 64 + cc) * 72 + r];
            }
            *(uint4*)(rectT + (size_t)(tb + r) * 256 + 8 * m) = *(const uint4*)tmp;
        }
    }
}

// ---------------------------------------------------------------- K3: fused EMA + adaptive-threshold scan
static __device__ __forceinline__ float bfw(unsigned int w, int odd) {
    return __uint_as_float(odd ? (w & 0xFFFF0000u) : (w << 16));
}

__device__ __forceinline__ void scan_step(float r0, float r1, float r2, float r3,
        int u, bool store, int c, float* __restrict__ out0, float* __restrict__ out1,
        float& s0, float& s1, float& s2, float& s3, float& thr) {
    s0 = AF * r0 + OMF * s0;
    s1 = AF * r1 + OMF * s1;
    s2 = AF * r2 + OMF * s2;
    s3 = AF * r3 + OMF * s3;
    const float k0 = (s0 > thr) ? 1.0f : 0.0f;
    const float k1 = (s1 > thr) ? 1.0f : 0.0f;
    const float k2 = (s2 > thr) ? 1.0f : 0.0f;
    const float k3 = (s3 > thr) ? 1.0f : 0.0f;
    const float cnt = (k0 + k1) + (k2 + k3);
    thr = thr + 0.01f * (cnt * 0.25f) + 0.01f * (0.1f - thr);
    if (store) {
        const int e  = (u >= T_LEN) ? 1 : 0;
        const int tt = u - (e ? T_LEN : 0);
        const int o1 = ((e * T_LEN + tt) << 6) + c;          // [B][2][T][C]
        out1[o1]                   = s0;
        out1[o1 + 2 * T_LEN * NCH] = s1;
        out1[o1 + 4 * T_LEN * NCH] = s2;
        out1[o1 + 6 * T_LEN * NCH] = s3;
        const int o0 = (tt << 7) + (e << 6) + c;             // [B][T][2C]
        out0[o0]                   = k0;
        out0[o0 + T_LEN * 128]     = k1;
        out0[o0 + 2 * T_LEN * 128] = k2;
        out0[o0 + 3 * T_LEN * 128] = k3;
    }
}

// 16 steps per group; groups never straddle the ear boundary (48000 % 16 == 0)
#define LOAD_G16(buf, ug) do {                                                       \
    const int tt_ = ((ug) < T_LEN) ? (ug) : ((ug) - T_LEN);                          \
    const unsigned short* bp_ = rectT + (size_t)tt_ * 256 + c * 4;                   \
    _Pragma("unroll")                                                                \
    for (int q_ = 0; q_ < 16; ++q_) buf[q_] = *(const uint2*)(bp_ + q_ * 256);       \
} while (0)

#define PROC_G16(buf, ug) do {                                                       \
    _Pragma("unroll")                                                                \
    for (int q_ = 0; q_ < 16; ++q_) {                                                \
        const float r0_ = bfw(buf[q_].x, 0);                                         \
        const float r1_ = bfw(buf[q_].x, 1);                                         \
        const float r2_ = bfw(buf[q_].y, 0);                                         \
        const float r3_ = bfw(buf[q_].y, 1);                                         \
        scan_step(r0_, r1_, r2_, r3_, (ug) + q_, STORE, c, out0, out1, s0, s1, s2, s3, thr); \
    }                                                                                \
} while (0)

template <bool STORE>
__device__ __forceinline__ void scan_range(int from, int to, int c,
        const unsigned short* __restrict__ rectT, float* __restrict__ out0, float* __restrict__ out1,
        float& s0, float& s1, float& s2, float& s3, float& thr) {
    if (from >= to) return;                // (to-from) is a multiple of 32
    uint2 bufA[16], bufB[16];
    LOAD_G16(bufA, from);
    for (int ug = from; ug < to; ug += 32) {
        LOAD_G16(bufB, ug + 16);
        PROC_G16(bufA, ug);
        if (ug + 32 < to) LOAD_G16(bufA, ug + 32);
        PROC_G16(bufB, ug + 16);
    }
}

__global__ __launch_bounds__(256) void scan_kernel(const unsigned short* __restrict__ rectT,
                                                   float* __restrict__ out) {
    const int k = blockIdx.x * 4 + (int)(threadIdx.x >> 6);   // chunk id
    if (k >= (2 * T_LEN) / CT) return;
    const int c    = threadIdx.x & 63;                  // channel
    const int u0   = k * CT;
    const int uend = u0 + CT;
    const int w0   = (u0 >= WU) ? (u0 - WU) : 0;
    float s0 = 0.f, s1 = 0.f, s2 = 0.f, s3 = 0.f, thr = 0.1f;
    float* out0 = out;
    float* out1 = out + (size_t)NB * T_LEN * 2 * NCH;   // 24,576,000
    scan_range<false>(w0, u0,   c, rectT, out0, out1, s0, s1, s2, s3, thr);
    scan_range<true >(u0, uend, c, rectT, out0, out1, s0, s1, s2, s3, thr);
}

// ---------------------------------------------------------------- launch
extern "C" void kernel_launch(void* const* d_in, const int* in_sizes, int n_in,
                              void* d_out, int out_size, void* d_ws, size_t ws_size,
                              hipStream_t stream) {
    const float* x  = (const float*)d_in[0];       // [4, 48000] fp32
    const float* Km = (const float*)d_in[1];       // [64, L]    fp32
    const int L     = in_sizes[1] / NCH;
    const int SMAX  = (L + 31) / 32;
    const int SMAX4 = (SMAX + 3) & ~3;
    const int SMAXA = SMAX4 + 4;                   // +4-row guard for A prefetch
    const int PAD   = (L + 1) & ~1;                // even, >= L-1
    const int XCAP  = PAD + T_LEN + 512;           // even; covers padded-K over-read

    char* w = (char*)d_ws;
    int* kstart = (int*)w;
    unsigned short* xc = (unsigned short*)(w + 512);
    const size_t xc_bytes = (size_t)NB * 2 * XCAP * 2;
    unsigned short* Afrag = (unsigned short*)(w + 512 + ((xc_bytes + 15) & ~(size_t)15));
    const size_t a_bytes = (size_t)4 * SMAXA * 64 * 8 * 2;
    unsigned short* rect = (unsigned short*)((char*)Afrag + ((a_bytes + 15) & ~(size_t)15));
    const size_t rect_bytes = (size_t)NB * NCH * T_LEN * 2;   // 24.576 MB
    unsigned short* rectT = (unsigned short*)((char*)rect + rect_bytes);

    const int pxBlocks = (NB * XCAP + 255) / 256;
    dim3 pgrid(pxBlocks > SMAX4 ? pxBlocks : SMAX4, 5);
    prep_all<<<pgrid, 256, 0, stream>>>(x, Km, kstart, xc, Afrag, L, SMAX4, SMAXA, PAD, XCAP);
    conv_mfma<<<dim3(T_LEN / 128, 4), 256, 0, stream>>>(xc, Afrag, kstart, rect, L, SMAXA, PAD, XCAP);
    transpose_rect<<<T_LEN / 64, 256, 0, stream>>>(rect, rectT);
    const int nchunks = (2 * T_LEN) / CT;          // 750
    scan_kernel<<<(nchunks + 3) / 4, 256, 0, stream>>>(rectT, (float*)d_out);
}

// Round 9
// 87.563 us; speedup vs baseline: 3.8384x; 1.2644x over previous
//
#include <hip/hip_runtime.h>
#include <hip/hip_bf16.h>

#define T_LEN 48000
#define NCH   64
#define NB    4
#define CT    64     // scan chunk length (96000/64 = 1500 chunks)
#define WU    128    // scan warm-up (0.96^128=5.4e-3 -> s err <0.5; thr err -> spike flips only)
#define TTILE 256    // conv time-span per block (16 MFMA tiles per wave)

static constexpr double DTd    = 1.0 / 48000.0;
static constexpr double ALPHAd = DTd / (DTd + 0.0005);   // exactly 0.04
static constexpr float  AF     = (float)ALPHAd;
static constexpr float  OMF    = (float)(1.0 - ALPHAd);  // 0.96

typedef __attribute__((ext_vector_type(8))) short bf16x8;
typedef __attribute__((ext_vector_type(4))) float f32x4;
typedef bf16x8 bf16x8_u __attribute__((aligned(4)));     // 4B-aligned 16B load

static __device__ __forceinline__ unsigned short f2bf(float f) {
    __hip_bfloat16 h = __float2bfloat16(f);
    unsigned short u; __builtin_memcpy(&u, &h, 2);
    return u;
}

// ---------------------------------------------------------------- K0: fused prep
// role 0..3: Afrag swizzle for group g (+kstart); role 4: x -> parity bf16 copies
__global__ __launch_bounds__(256) void prep_all(
        const float* __restrict__ x, const float* __restrict__ Km,
        int* __restrict__ kstart, unsigned short* __restrict__ xc,
        unsigned short* __restrict__ Afrag,
        int L, int SMAX8, int SMAXA, int PAD, int XCAP) {
    const int role = blockIdx.y;
    if (role < 4) {
        const int g = role, s = blockIdx.x;
        if (s >= SMAX8) return;
        __shared__ int smin;
        if (threadIdx.x == 0) smin = L - 1;
        __syncthreads();
        const float* row = Km + (size_t)(g * 16) * L;
        int local = L - 1;
        for (int i = threadIdx.x; i < L; i += 256)
            if (row[i] != 0.0f) { local = i; break; }
        atomicMin(&smin, local);
        __syncthreads();
        const int ks = smin;
        if (s == 0 && threadIdx.x == 0) kstart[g * 16] = ks;
        if (threadIdx.x < 64) {
            const int lane = threadIdx.x;
            const int Lg = L - ks;
            const int r = lane & 15, khi = lane >> 4;
            const float* kr = Km + (size_t)(g * 16 + r) * L + ks;
            const size_t off = ((size_t)(g * SMAXA + s) * 64 + lane) * 8;
            #pragma unroll
            for (int jj = 0; jj < 8; ++jj) {
                const int q = 32 * s + 8 * khi + jj;
                Afrag[off + jj] = (q < Lg) ? f2bf(kr[q]) : (unsigned short)0;
            }
        }
    } else {
        const int idx = blockIdx.x * 256 + threadIdx.x;
        if (idx >= NB * XCAP) return;
        const int b = idx / XCAP, j = idx % XCAP;
        const float* xb = x + (size_t)b * T_LEN;
        const int t0 = j - PAD, t1 = t0 + 1;
        xc[((size_t)b * 2 + 0) * XCAP + j] = (t0 >= 0 && t0 < T_LEN) ? f2bf(xb[t0]) : (unsigned short)0;
        xc[((size_t)b * 2 + 1) * XCAP + j] = (t1 >= 0 && t1 < T_LEN) ? f2bf(xb[t1]) : (unsigned short)0;
    }
}

// ---------------------------------------------------------------- K1: MFMA filterbank -> rectT [T][C*4+B] bf16
// 16 time-tiles/wave (ring of 16 B-windows, 2 loads per 16 MFMA), 8 K-steps per
// barrier phase (slot algebra needs 2s%16==0). A staged via double-buffered LDS.
// Epilogue re-stages acc through LDS (union with As) and writes rectT directly.
__global__ __launch_bounds__(256, 2) void conv_mfma(
        const unsigned short* __restrict__ xc, const unsigned short* __restrict__ Afrag,
        const int* __restrict__ kstart, unsigned short* __restrict__ rectT,
        int L, int SMAXA, int PAD, int XCAP) {
    const int lane = threadIdx.x & 63;
    const int w    = threadIdx.x >> 6;                 // wave = batch
    const int g    = blockIdx.y;
    const int t0   = blockIdx.x * TTILE;
    const int ks   = kstart[g * 16];
    const int Lg   = L - ks;
    const int nst8 = (((Lg + 31) >> 5) + 7) & ~7;      // K-steps, padded to x8 (A zero rows)
    const int nl   = lane & 15, khi = lane >> 4;
    const int i0   = t0 + nl + 8 * khi - (Lg - 1);     // x index for (K-step 0, tile 0)
    const int p    = i0 & 1;                           // parity fixed across steps/tiles
    const unsigned short* xp  = xc + ((size_t)(w * 2 + p)) * XCAP + (PAD + i0 - p);
    // wave w stages A K-step rows (s+2w) and (s+2w+1)
    const unsigned short* apw = Afrag + ((size_t)(g * SMAXA) + 2 * w) * 512 + (size_t)lane * 8;

    __shared__ __align__(16) short smem[256 * 72];     // union: As[2][8*512] | S[256][72]
    short* As = smem;

    f32x4 acc[16];
    #pragma unroll
    for (int j = 0; j < 16; ++j) acc[j] = (f32x4){0.f, 0.f, 0.f, 0.f};
    bf16x8 bx[16];
    #pragma unroll
    for (int j = 0; j < 16; ++j) bx[j] = *(const bf16x8_u*)(xp + 16 * j);

    {   // initial stage: K-step rows 0..7 (wave w: rows 2w, 2w+1)
        const bf16x8 s0 = *(const bf16x8*)(apw);
        const bf16x8 s1 = *(const bf16x8*)(apw + 512);
        *(bf16x8*)(&As[(2 * w)     * 512 + lane * 8]) = s0;
        *(bf16x8*)(&As[(2 * w + 1) * 512 + lane * 8]) = s1;
    }
    __syncthreads();

#define MFMA16(areg, SH)                                                                \
    _Pragma("unroll")                                                                   \
    for (int j = 0; j < 16; ++j)                                                        \
        acc[j] = __builtin_amdgcn_mfma_f32_16x16x32_bf16(areg, bx[((SH) + j) & 15], acc[j], 0, 0, 0);

    int q = 0;
    for (int s = 0; s < nst8; s += 8) {
        // prefetch next phase's 2 A rows (guard rows exist beyond nst8)
        const bf16x8 n0 = *(const bf16x8*)(apw + (size_t)(s + 8) * 512);
        const bf16x8 n1 = *(const bf16x8*)(apw + (size_t)(s + 9) * 512);
        const short* Ab = As + q * 4096;
        {   // u = 0..3
            const bf16x8 a0 = *(const bf16x8*)(&Ab[       lane * 8]);
            const bf16x8 a1 = *(const bf16x8*)(&Ab[ 512 + lane * 8]);
            const bf16x8 a2 = *(const bf16x8*)(&Ab[1024 + lane * 8]);
            const bf16x8 a3 = *(const bf16x8*)(&Ab[1536 + lane * 8]);
            MFMA16(a0, 0);
            bx[ 0] = *(const bf16x8_u*)(xp + 256); bx[ 1] = *(const bf16x8_u*)(xp + 272);
            MFMA16(a1, 2);
            bx[ 2] = *(const bf16x8_u*)(xp + 288); bx[ 3] = *(const bf16x8_u*)(xp + 304);
            MFMA16(a2, 4);
            bx[ 4] = *(const bf16x8_u*)(xp + 320); bx[ 5] = *(const bf16x8_u*)(xp + 336);
            MFMA16(a3, 6);
            bx[ 6] = *(const bf16x8_u*)(xp + 352); bx[ 7] = *(const bf16x8_u*)(xp + 368);
        }
        {   // u = 4..7
            const bf16x8 a4 = *(const bf16x8*)(&Ab[2048 + lane * 8]);
            const bf16x8 a5 = *(const bf16x8*)(&Ab[2560 + lane * 8]);
            const bf16x8 a6 = *(const bf16x8*)(&Ab[3072 + lane * 8]);
            const bf16x8 a7 = *(const bf16x8*)(&Ab[3584 + lane * 8]);
            MFMA16(a4, 8);
            bx[ 8] = *(const bf16x8_u*)(xp + 384); bx[ 9] = *(const bf16x8_u*)(xp + 400);
            MFMA16(a5, 10);
            bx[10] = *(const bf16x8_u*)(xp + 416); bx[11] = *(const bf16x8_u*)(xp + 432);
            MFMA16(a6, 12);
            bx[12] = *(const bf16x8_u*)(xp + 448); bx[13] = *(const bf16x8_u*)(xp + 464);
            MFMA16(a7, 14);
            bx[14] = *(const bf16x8_u*)(xp + 480); bx[15] = *(const bf16x8_u*)(xp + 496);
        }
        // stage next phase's A rows into the other buffer, block-wide handoff
        *(bf16x8*)(&As[(q ^ 1) * 4096 + (2 * w)     * 512 + lane * 8]) = n0;
        *(bf16x8*)(&As[(q ^ 1) * 4096 + (2 * w + 1) * 512 + lane * 8]) = n1;
        __syncthreads();
        q ^= 1;
        xp += 256;                                     // 8 K-steps x 32 taps
    }
#undef MFMA16

    // ---- epilogue: acc -> S[t_local][ (c_local)*4 + b ] -> rectT rows ----
    // D layout: col(time)=lane&15, row(channel)=4*(lane>>4)+v  [m89-verified]
    short* S = smem;                                   // stride 72 shorts/row (16B-mult)
    #pragma unroll
    for (int j = 0; j < 16; ++j) {
        #pragma unroll
        for (int v = 0; v < 4; ++v)
            S[(16 * j + nl) * 72 + (4 * khi + v) * 4 + w] =
                (short)f2bf(fmaxf(acc[j][v], 0.f));
    }
    __syncthreads();
    {   // cooperative copy: 8 iters x 32 rows; 128B contiguous per row-segment
        const int rr = threadIdx.x >> 3, ch = threadIdx.x & 7;
        #pragma unroll
        for (int it = 0; it < 8; ++it) {
            const int r = it * 32 + rr;
            if (t0 + r < T_LEN) {
                const uint4 v = *(const uint4*)(&S[r * 72 + 8 * ch]);
                *(uint4*)(rectT + ((size_t)(t0 + r)) * 256 + 64 * g + 8 * ch) = v;
            }
        }
    }
}

// ---------------------------------------------------------------- K2: fused EMA + adaptive-threshold scan
static __device__ __forceinline__ float bfw(unsigned int w, int odd) {
    return __uint_as_float(odd ? (w & 0xFFFF0000u) : (w << 16));
}

__device__ __forceinline__ void scan_step(float r0, float r1, float r2, float r3,
        int u, bool store, int c, float* __restrict__ out0, float* __restrict__ out1,
        float& s0, float& s1, float& s2, float& s3, float& thr) {
    s0 = AF * r0 + OMF * s0;
    s1 = AF * r1 + OMF * s1;
    s2 = AF * r2 + OMF * s2;
    s3 = AF * r3 + OMF * s3;
    const float k0 = (s0 > thr) ? 1.0f : 0.0f;
    const float k1 = (s1 > thr) ? 1.0f : 0.0f;
    const float k2 = (s2 > thr) ? 1.0f : 0.0f;
    const float k3 = (s3 > thr) ? 1.0f : 0.0f;
    const float cnt = (k0 + k1) + (k2 + k3);
    thr = thr + 0.01f * (cnt * 0.25f) + 0.01f * (0.1f - thr);
    if (store) {
        const int e  = (u >= T_LEN) ? 1 : 0;
        const int tt = u - (e ? T_LEN : 0);
        const int o1 = ((e * T_LEN + tt) << 6) + c;          // [B][2][T][C]
        out1[o1]                   = s0;
        out1[o1 + 2 * T_LEN * NCH] = s1;
        out1[o1 + 4 * T_LEN * NCH] = s2;
        out1[o1 + 6 * T_LEN * NCH] = s3;
        const int o0 = (tt << 7) + (e << 6) + c;             // [B][T][2C]
        out0[o0]                   = k0;
        out0[o0 + T_LEN * 128]     = k1;
        out0[o0 + 2 * T_LEN * 128] = k2;
        out0[o0 + 3 * T_LEN * 128] = k3;
    }
}

// 16 steps per group; groups never straddle the ear boundary (48000 % 16 == 0)
#define LOAD_G16(buf, ug) do {                                                       \
    const int tt_ = ((ug) < T_LEN) ? (ug) : ((ug) - T_LEN);                          \
    const unsigned short* bp_ = rectT + (size_t)tt_ * 256 + c * 4;                   \
    _Pragma("unroll")                                                                \
    for (int q_ = 0; q_ < 16; ++q_) buf[q_] = *(const uint2*)(bp_ + q_ * 256);       \
} while (0)

#define PROC_G16(buf, ug) do {                                                       \
    _Pragma("unroll")                                                                \
    for (int q_ = 0; q_ < 16; ++q_) {                                                \
        const float r0_ = bfw(buf[q_].x, 0);                                         \
        const float r1_ = bfw(buf[q_].x, 1);                                         \
        const float r2_ = bfw(buf[q_].y, 0);                                         \
        const float r3_ = bfw(buf[q_].y, 1);                                         \
        scan_step(r0_, r1_, r2_, r3_, (ug) + q_, STORE, c, out0, out1, s0, s1, s2, s3, thr); \
    }                                                                                \
} while (0)

template <bool STORE>
__device__ __forceinline__ void scan_range(int from, int to, int c,
        const unsigned short* __restrict__ rectT, float* __restrict__ out0, float* __restrict__ out1,
        float& s0, float& s1, float& s2, float& s3, float& thr) {
    if (from >= to) return;                // (to-from) is a multiple of 32
    uint2 bufA[16], bufB[16];
    LOAD_G16(bufA, from);
    for (int ug = from; ug < to; ug += 32) {
        LOAD_G16(bufB, ug + 16);
        PROC_G16(bufA, ug);
        if (ug + 32 < to) LOAD_G16(bufA, ug + 32);
        PROC_G16(bufB, ug + 16);
    }
}

__global__ __launch_bounds__(256) void scan_kernel(const unsigned short* __restrict__ rectT,
                                                   float* __restrict__ out) {
    const int k = blockIdx.x * 4 + (int)(threadIdx.x >> 6);   // chunk id
    if (k >= (2 * T_LEN) / CT) return;
    const int c    = threadIdx.x & 63;                  // channel
    const int u0   = k * CT;
    const int uend = u0 + CT;
    const int w0   = (u0 >= WU) ? (u0 - WU) : 0;
    float s0 = 0.f, s1 = 0.f, s2 = 0.f, s3 = 0.f, thr = 0.1f;
    float* out0 = out;
    float* out1 = out + (size_t)NB * T_LEN * 2 * NCH;   // 24,576,000
    scan_range<false>(w0, u0,   c, rectT, out0, out1, s0, s1, s2, s3, thr);
    scan_range<true >(u0, uend, c, rectT, out0, out1, s0, s1, s2, s3, thr);
}

// ---------------------------------------------------------------- launch
extern "C" void kernel_launch(void* const* d_in, const int* in_sizes, int n_in,
                              void* d_out, int out_size, void* d_ws, size_t ws_size,
                              hipStream_t stream) {
    const float* x  = (const float*)d_in[0];       // [4, 48000] fp32
    const float* Km = (const float*)d_in[1];       // [64, L]    fp32
    const int L     = in_sizes[1] / NCH;
    const int SMAX  = (L + 31) / 32;
    const int SMAX8 = (SMAX + 7) & ~7;
    const int SMAXA = SMAX8 + 8;                   // +8-row guard for A prefetch
    const int PAD   = (L + 1) & ~1;                // even, >= L-1
    const int XCAP  = PAD + T_LEN + 1024;          // even; covers padded-K over-read

    char* w = (char*)d_ws;
    int* kstart = (int*)w;
    unsigned short* xc = (unsigned short*)(w + 512);
    const size_t xc_bytes = (size_t)NB * 2 * XCAP * 2;
    unsigned short* Afrag = (unsigned short*)(w + 512 + ((xc_bytes + 15) & ~(size_t)15));
    const size_t a_bytes = (size_t)4 * SMAXA * 64 * 8 * 2;
    unsigned short* rectT = (unsigned short*)((char*)Afrag + ((a_bytes + 15) & ~(size_t)15));

    const int pxBlocks = (NB * XCAP + 255) / 256;
    dim3 pgrid(pxBlocks > SMAX8 ? pxBlocks : SMAX8, 5);
    prep_all<<<pgrid, 256, 0, stream>>>(x, Km, kstart, xc, Afrag, L, SMAX8, SMAXA, PAD, XCAP);
    conv_mfma<<<dim3((T_LEN + TTILE - 1) / TTILE, 4), 256, 0, stream>>>(
        xc, Afrag, kstart, rectT, L, SMAXA, PAD, XCAP);
    const int nchunks = (2 * T_LEN) / CT;          // 1500
    scan_kernel<<<(nchunks + 3) / 4, 256, 0, stream>>>(rectT, (float*)d_out);
}

// Round 10
// 84.491 us; speedup vs baseline: 3.9780x; 1.0364x over previous
//
#include <hip/hip_runtime.h>
#include <hip/hip_bf16.h>

#define T_LEN 48000
#define NCH   64
#define NB    4
#define CT    96     // scan chunk length (96000/96 = 1000 chunks; ear boundary = chunk 500)
#define WU    128    // scan warm-up (0.96^128=5.4e-3 -> s err ~0.47; thr err -> spike flips only)
#define TTILE 256    // conv time-span per block (16 MFMA tiles per wave)

static constexpr double DTd    = 1.0 / 48000.0;
static constexpr double ALPHAd = DTd / (DTd + 0.0005);   // exactly 0.04
static constexpr float  AF     = (float)ALPHAd;
static constexpr float  OMF    = (float)(1.0 - ALPHAd);  // 0.96

typedef __attribute__((ext_vector_type(8))) short bf16x8;
typedef __attribute__((ext_vector_type(4))) float f32x4;
typedef bf16x8 bf16x8_u __attribute__((aligned(4)));     // 4B-aligned 16B load

static __device__ __forceinline__ unsigned short f2bf(float f) {
    __hip_bfloat16 h = __float2bfloat16(f);
    unsigned short u; __builtin_memcpy(&u, &h, 2);
    return u;
}

// ---------------------------------------------------------------- K0: fused prep
// role 0..3: Afrag swizzle for group g (+kstart); role 4: x -> parity bf16 copies
__global__ __launch_bounds__(256) void prep_all(
        const float* __restrict__ x, const float* __restrict__ Km,
        int* __restrict__ kstart, unsigned short* __restrict__ xc,
        unsigned short* __restrict__ Afrag,
        int L, int SMAX8, int SMAXA, int PAD, int XCAP) {
    const int role = blockIdx.y;
    if (role < 4) {
        const int g = role, s = blockIdx.x;
        if (s >= SMAX8) return;
        __shared__ int smin;
        if (threadIdx.x == 0) smin = L - 1;
        __syncthreads();
        const float* row = Km + (size_t)(g * 16) * L;
        int local = L - 1;
        for (int i = threadIdx.x; i < L; i += 256)
            if (row[i] != 0.0f) { local = i; break; }
        atomicMin(&smin, local);
        __syncthreads();
        const int ks = smin;
        if (s == 0 && threadIdx.x == 0) kstart[g * 16] = ks;
        if (threadIdx.x < 64) {
            const int lane = threadIdx.x;
            const int Lg = L - ks;
            const int r = lane & 15, khi = lane >> 4;
            const float* kr = Km + (size_t)(g * 16 + r) * L + ks;
            const size_t off = ((size_t)(g * SMAXA + s) * 64 + lane) * 8;
            #pragma unroll
            for (int jj = 0; jj < 8; ++jj) {
                const int q = 32 * s + 8 * khi + jj;
                Afrag[off + jj] = (q < Lg) ? f2bf(kr[q]) : (unsigned short)0;
            }
        }
    } else {
        const int idx = blockIdx.x * 256 + threadIdx.x;
        if (idx >= NB * XCAP) return;
        const int b = idx / XCAP, j = idx % XCAP;
        const float* xb = x + (size_t)b * T_LEN;
        const int t0 = j - PAD, t1 = t0 + 1;
        xc[((size_t)b * 2 + 0) * XCAP + j] = (t0 >= 0 && t0 < T_LEN) ? f2bf(xb[t0]) : (unsigned short)0;
        xc[((size_t)b * 2 + 1) * XCAP + j] = (t1 >= 0 && t1 < T_LEN) ? f2bf(xb[t1]) : (unsigned short)0;
    }
}

// ---------------------------------------------------------------- K1: MFMA filterbank -> rectT [T][C*4+B] bf16
// 16 time-tiles/wave; ring of 16 B-windows. Refills are issued right after the
// two releasing MFMAs (j=0,1) of each group: first re-use is 14 MFMA into the
// NEXT group -> ~136cy slack covers L2 latency (was 68cy -> dependent stalls).
__global__ __launch_bounds__(256, 2) void conv_mfma(
        const unsigned short* __restrict__ xc, const unsigned short* __restrict__ Afrag,
        const int* __restrict__ kstart, unsigned short* __restrict__ rectT,
        int L, int SMAXA, int PAD, int XCAP) {
    const int lane = threadIdx.x & 63;
    const int w    = threadIdx.x >> 6;                 // wave = batch
    const int g    = blockIdx.y;
    const int t0   = blockIdx.x * TTILE;
    const int ks   = kstart[g * 16];
    const int Lg   = L - ks;
    const int nst8 = (((Lg + 31) >> 5) + 7) & ~7;      // K-steps, padded to x8 (A zero rows)
    const int nl   = lane & 15, khi = lane >> 4;
    const int i0   = t0 + nl + 8 * khi - (Lg - 1);     // x index for (K-step 0, tile 0)
    const int p    = i0 & 1;                           // parity fixed across steps/tiles
    const unsigned short* xp  = xc + ((size_t)(w * 2 + p)) * XCAP + (PAD + i0 - p);
    // wave w stages A K-step rows (s+2w) and (s+2w+1)
    const unsigned short* apw = Afrag + ((size_t)(g * SMAXA) + 2 * w) * 512 + (size_t)lane * 8;

    __shared__ __align__(16) short smem[256 * 72];     // union: As[2][8*512] | S[256][72]
    short* As = smem;

    f32x4 acc[16];
    #pragma unroll
    for (int j = 0; j < 16; ++j) acc[j] = (f32x4){0.f, 0.f, 0.f, 0.f};
    bf16x8 bx[16];
    #pragma unroll
    for (int j = 0; j < 16; ++j) bx[j] = *(const bf16x8_u*)(xp + 16 * j);

    {   // initial stage: K-step rows 0..7 (wave w: rows 2w, 2w+1)
        const bf16x8 s0 = *(const bf16x8*)(apw);
        const bf16x8 s1 = *(const bf16x8*)(apw + 512);
        *(bf16x8*)(&As[(2 * w)     * 512 + lane * 8]) = s0;
        *(bf16x8*)(&As[(2 * w + 1) * 512 + lane * 8]) = s1;
    }
    __syncthreads();

// group U (K-step U of phase): tiles j use slot (2U+j)&15; slots (2U)&15,(2U+1)&15
// are released at j=0,1 -> refill with next phase's windows immediately after.
#define GROUP(areg, U)                                                                   \
    acc[0] = __builtin_amdgcn_mfma_f32_16x16x32_bf16(areg, bx[(2*(U))     & 15], acc[0], 0, 0, 0); \
    acc[1] = __builtin_amdgcn_mfma_f32_16x16x32_bf16(areg, bx[(2*(U) + 1) & 15], acc[1], 0, 0, 0); \
    bx[(2*(U))     & 15] = *(const bf16x8_u*)(xp + 256 + 32 * (U));                      \
    bx[(2*(U) + 1) & 15] = *(const bf16x8_u*)(xp + 272 + 32 * (U));                      \
    _Pragma("unroll")                                                                    \
    for (int j = 2; j < 16; ++j)                                                         \
        acc[j] = __builtin_amdgcn_mfma_f32_16x16x32_bf16(areg, bx[(2*(U) + j) & 15], acc[j], 0, 0, 0);

    int q = 0;
    for (int s = 0; s < nst8; s += 8) {
        // prefetch next phase's 2 A rows (guard rows exist beyond nst8)
        const bf16x8 n0 = *(const bf16x8*)(apw + (size_t)(s + 8) * 512);
        const bf16x8 n1 = *(const bf16x8*)(apw + (size_t)(s + 9) * 512);
        const short* Ab = As + q * 4096;
        {   // K-steps 0..3 of the phase
            const bf16x8 a0 = *(const bf16x8*)(&Ab[       lane * 8]);
            const bf16x8 a1 = *(const bf16x8*)(&Ab[ 512 + lane * 8]);
            const bf16x8 a2 = *(const bf16x8*)(&Ab[1024 + lane * 8]);
            const bf16x8 a3 = *(const bf16x8*)(&Ab[1536 + lane * 8]);
            GROUP(a0, 0)
            GROUP(a1, 1)
            GROUP(a2, 2)
            GROUP(a3, 3)
        }
        {   // K-steps 4..7
            const bf16x8 a4 = *(const bf16x8*)(&Ab[2048 + lane * 8]);
            const bf16x8 a5 = *(const bf16x8*)(&Ab[2560 + lane * 8]);
            const bf16x8 a6 = *(const bf16x8*)(&Ab[3072 + lane * 8]);
            const bf16x8 a7 = *(const bf16x8*)(&Ab[3584 + lane * 8]);
            GROUP(a4, 4)
            GROUP(a5, 5)
            GROUP(a6, 6)
            GROUP(a7, 7)
        }
        // stage next phase's A rows into the other buffer, block-wide handoff
        *(bf16x8*)(&As[(q ^ 1) * 4096 + (2 * w)     * 512 + lane * 8]) = n0;
        *(bf16x8*)(&As[(q ^ 1) * 4096 + (2 * w + 1) * 512 + lane * 8]) = n1;
        __syncthreads();
        q ^= 1;
        xp += 256;                                     // 8 K-steps x 32 taps
    }
#undef GROUP

    // ---- epilogue: acc -> S[t_local][ (c_local)*4 + b ] -> rectT rows ----
    // D layout: col(time)=lane&15, row(channel)=4*(lane>>4)+v  [m89-verified]
    short* S = smem;                                   // stride 72 shorts/row (16B-mult)
    #pragma unroll
    for (int j = 0; j < 16; ++j) {
        #pragma unroll
        for (int v = 0; v < 4; ++v)
            S[(16 * j + nl) * 72 + (4 * khi + v) * 4 + w] =
                (short)f2bf(fmaxf(acc[j][v], 0.f));
    }
    __syncthreads();
    {   // cooperative copy: 8 iters x 32 rows; 128B contiguous per row-segment
        const int rr = threadIdx.x >> 3, ch = threadIdx.x & 7;
        #pragma unroll
        for (int it = 0; it < 8; ++it) {
            const int r = it * 32 + rr;
            if (t0 + r < T_LEN) {
                const uint4 v = *(const uint4*)(&S[r * 72 + 8 * ch]);
                *(uint4*)(rectT + ((size_t)(t0 + r)) * 256 + 64 * g + 8 * ch) = v;
            }
        }
    }
}

// ---------------------------------------------------------------- K2: fused EMA + adaptive-threshold scan
static __device__ __forceinline__ float bfw(unsigned int w, int odd) {
    return __uint_as_float(odd ? (w & 0xFFFF0000u) : (w << 16));
}

__device__ __forceinline__ void scan_step(float r0, float r1, float r2, float r3,
        int u, bool store, int c, float* __restrict__ out0, float* __restrict__ out1,
        float& s0, float& s1, float& s2, float& s3, float& thr) {
    s0 = AF * r0 + OMF * s0;
    s1 = AF * r1 + OMF * s1;
    s2 = AF * r2 + OMF * s2;
    s3 = AF * r3 + OMF * s3;
    const float k0 = (s0 > thr) ? 1.0f : 0.0f;
    const float k1 = (s1 > thr) ? 1.0f : 0.0f;
    const float k2 = (s2 > thr) ? 1.0f : 0.0f;
    const float k3 = (s3 > thr) ? 1.0f : 0.0f;
    const float cnt = (k0 + k1) + (k2 + k3);
    thr = thr + 0.01f * (cnt * 0.25f) + 0.01f * (0.1f - thr);
    if (store) {
        const int e  = (u >= T_LEN) ? 1 : 0;
        const int tt = u - (e ? T_LEN : 0);
        const int o1 = ((e * T_LEN + tt) << 6) + c;          // [B][2][T][C]
        out1[o1]                   = s0;
        out1[o1 + 2 * T_LEN * NCH] = s1;
        out1[o1 + 4 * T_LEN * NCH] = s2;
        out1[o1 + 6 * T_LEN * NCH] = s3;
        const int o0 = (tt << 7) + (e << 6) + c;             // [B][T][2C]
        out0[o0]                   = k0;
        out0[o0 + T_LEN * 128]     = k1;
        out0[o0 + 2 * T_LEN * 128] = k2;
        out0[o0 + 3 * T_LEN * 128] = k3;
    }
}

// 16 steps per group; groups never straddle the ear boundary (48000 % 16 == 0,
// CT and WU are multiples of 16, and 48000 % CT == 0)
#define LOAD_G16(buf, ug) do {                                                       \
    const int tt_ = ((ug) < T_LEN) ? (ug) : ((ug) - T_LEN);                          \
    const unsigned short* bp_ = rectT + (size_t)tt_ * 256 + c * 4;                   \
    _Pragma("unroll")                                                                \
    for (int q_ = 0; q_ < 16; ++q_) buf[q_] = *(const uint2*)(bp_ + q_ * 256);       \
} while (0)

#define PROC_G16(buf, ug) do {                                                       \
    _Pragma("unroll")                                                                \
    for (int q_ = 0; q_ < 16; ++q_) {                                                \
        const float r0_ = bfw(buf[q_].x, 0);                                         \
        const float r1_ = bfw(buf[q_].x, 1);                                         \
        const float r2_ = bfw(buf[q_].y, 0);                                         \
        const float r3_ = bfw(buf[q_].y, 1);                                         \
        scan_step(r0_, r1_, r2_, r3_, (ug) + q_, STORE, c, out0, out1, s0, s1, s2, s3, thr); \
    }                                                                                \
} while (0)

template <bool STORE>
__device__ __forceinline__ void scan_range(int from, int to, int c,
        const unsigned short* __restrict__ rectT, float* __restrict__ out0, float* __restrict__ out1,
        float& s0, float& s1, float& s2, float& s3, float& thr) {
    if (from >= to) return;                // (to-from) is a multiple of 32
    uint2 bufA[16], bufB[16];
    LOAD_G16(bufA, from);
    for (int ug = from; ug < to; ug += 32) {
        LOAD_G16(bufB, ug + 16);
        PROC_G16(bufA, ug);
        if (ug + 32 < to) LOAD_G16(bufA, ug + 32);
        PROC_G16(bufB, ug + 16);
    }
}

__global__ __launch_bounds__(256) void scan_kernel(const unsigned short* __restrict__ rectT,
                                                   float* __restrict__ out) {
    const int k = blockIdx.x * 4 + (int)(threadIdx.x >> 6);   // chunk id
    if (k >= (2 * T_LEN) / CT) return;
    const int c    = threadIdx.x & 63;                  // channel
    const int u0   = k * CT;
    const int uend = u0 + CT;
    const int w0   = (u0 >= WU) ? (u0 - WU) : 0;
    float s0 = 0.f, s1 = 0.f, s2 = 0.f, s3 = 0.f, thr = 0.1f;
    float* out0 = out;
    float* out1 = out + (size_t)NB * T_LEN * 2 * NCH;   // 24,576,000
    scan_range<false>(w0, u0,   c, rectT, out0, out1, s0, s1, s2, s3, thr);
    scan_range<true >(u0, uend, c, rectT, out0, out1, s0, s1, s2, s3, thr);
}

// ---------------------------------------------------------------- launch
extern "C" void kernel_launch(void* const* d_in, const int* in_sizes, int n_in,
                              void* d_out, int out_size, void* d_ws, size_t ws_size,
                              hipStream_t stream) {
    const float* x  = (const float*)d_in[0];       // [4, 48000] fp32
    const float* Km = (const float*)d_in[1];       // [64, L]    fp32
    const int L     = in_sizes[1] / NCH;
    const int SMAX  = (L + 31) / 32;
    const int SMAX8 = (SMAX + 7) & ~7;
    const int SMAXA = SMAX8 + 8;                   // +8-row guard for A prefetch
    const int PAD   = (L + 1) & ~1;                // even, >= L-1
    const int XCAP  = PAD + T_LEN + 1024;          // even; covers padded-K over-read

    char* w = (char*)d_ws;
    int* kstart = (int*)w;
    unsigned short* xc = (unsigned short*)(w + 512);
    const size_t xc_bytes = (size_t)NB * 2 * XCAP * 2;
    unsigned short* Afrag = (unsigned short*)(w + 512 + ((xc_bytes + 15) & ~(size_t)15));
    const size_t a_bytes = (size_t)4 * SMAXA * 64 * 8 * 2;
    unsigned short* rectT = (unsigned short*)((char*)Afrag + ((a_bytes + 15) & ~(size_t)15));

    const int pxBlocks = (NB * XCAP + 255) / 256;
    dim3 pgrid(pxBlocks > SMAX8 ? pxBlocks : SMAX8, 5);
    prep_all<<<pgrid, 256, 0, stream>>>(x, Km, kstart, xc, Afrag, L, SMAX8, SMAXA, PAD, XCAP);
    conv_mfma<<<dim3((T_LEN + TTILE - 1) / TTILE, 4), 256, 0, stream>>>(
        xc, Afrag, kstart, rectT, L, SMAXA, PAD, XCAP);
    const int nchunks = (2 * T_LEN) / CT;          // 1000
    scan_kernel<<<(nchunks + 3) / 4, 256, 0, stream>>>(rectT, (float*)d_out);
}